// Round 7
// baseline (249.412 us; speedup 1.0000x reference)
//
#include <hip/hip_runtime.h>
#include <hip/hip_bf16.h>
#include <stdint.h>

// ---------------------------------------------------------------------------
// LayerNormLSTMCell: B=4096, I=H=1024, 4H=4096
//  hi = LN(input @ w_i2h + b_i2h; g_i2h, be_i2h)        [B,4H]
//  hh = LN(h_prev @ w_h2h + b_h2h; g_h2h, be_h2h)       [B,4H]
//  i,f,u,o = split(hi+hh, 4)
//  c = LN(c_prev*sigm(f+1) + tanh(u)*sigm(i); g_c,be_c) [B,H]
//  h = sigm(o)*tanh(c)
// LN: mean, UNBIASED std (ddof=1), divide by (std + 1e-6)
// ---------------------------------------------------------------------------

#define BDIM 4096
#define KDIM 1024
#define NDIM 4096
#define EPSV 1e-6f

typedef float f32x4 __attribute__((ext_vector_type(4)));
typedef __bf16 bf16x8 __attribute__((ext_vector_type(8)));
typedef unsigned short u16x8 __attribute__((ext_vector_type(8)));

__device__ inline unsigned short f2bf(float f) {
    unsigned u = __builtin_bit_cast(unsigned, f);
    u += 0x7FFFu + ((u >> 16) & 1u);   // round-to-nearest-even
    return (unsigned short)(u >> 16);
}
__device__ inline float bf2f(unsigned short u) {
    return __builtin_bit_cast(float, (unsigned)u << 16);
}
__device__ inline float sigm(float x) {
    return 1.0f / (1.0f + __expf(-x));
}
// fast tanh: 1 - 2/(e^{2x}+1); saturates correctly at +-inf
__device__ inline float ftanh(float x) {
    return 1.0f - 2.0f / (__expf(2.0f * x) + 1.0f);
}

// async global->LDS, 16B per lane. lds ptr must be wave-uniform.
__device__ inline void async16(const unsigned short* g, unsigned short* lds) {
    __builtin_amdgcn_global_load_lds(
        (const __attribute__((address_space(1))) void*)g,
        (__attribute__((address_space(3))) void*)lds,
        16, 0, 0);
}

// ---------------------------------------------------------------------------
// prep: z=0/1 cast input/h_prev f32->bf16 (8 elem/thread, 16B stores)
//       z=2/3 transpose+cast w f32 [1024][4096] -> bf16 [4096][1024]
// ---------------------------------------------------------------------------
__global__ __launch_bounds__(256) void prep(
    const float* __restrict__ in0, unsigned short* __restrict__ o0,
    const float* __restrict__ in1, unsigned short* __restrict__ o1,
    const float* __restrict__ w0, unsigned short* __restrict__ w0T,
    const float* __restrict__ w1, unsigned short* __restrict__ w1T)
{
    __shared__ float tile[64][65];
    const int z = blockIdx.z, tid = threadIdx.x;
    if (z < 2) {
        const float* src = z ? in1 : in0;
        unsigned short* dst = z ? o1 : o0;
        int i = (blockIdx.x * 256 + tid) * 8;
        float4 a = *(const float4*)(src + i);
        float4 b = *(const float4*)(src + i + 4);
        u16x8 v;
        v[0] = f2bf(a.x); v[1] = f2bf(a.y); v[2] = f2bf(a.z); v[3] = f2bf(a.w);
        v[4] = f2bf(b.x); v[5] = f2bf(b.y); v[6] = f2bf(b.z); v[7] = f2bf(b.w);
        *(u16x8*)(dst + i) = v;
        return;
    }
    const int bx = blockIdx.x;
    if (bx >= (NDIM / 64) * (KDIM / 64)) return;
    const float* src = (z == 3) ? w1 : w0;
    unsigned short* dst = (z == 3) ? w1T : w0T;
    const int c0 = (bx & (NDIM / 64 - 1)) * 64;   // col in [0,4096)
    const int r0 = (bx >> 6) * 64;                // row in [0,1024)
    const int tx = tid & 63, ty = tid >> 6;       // 64 x 4
    #pragma unroll
    for (int i = 0; i < 64; i += 4)
        tile[ty + i][tx] = src[(size_t)(r0 + ty + i) * NDIM + c0 + tx];
    __syncthreads();
    #pragma unroll
    for (int p = 0; p < 2; ++p) {
        int c = p * 32 + (tid >> 3);
        int rs = (tid & 7) * 8;
        u16x8 v;
        #pragma unroll
        for (int j = 0; j < 8; ++j) v[j] = f2bf(tile[rs + j][c]);
        *(u16x8*)(dst + (size_t)(c0 + c) * KDIM + r0 + rs) = v;
    }
}

// ---------------------------------------------------------------------------
// GEMM: C[m][n] = sum_k A[m][k] * Bt[n][k] + bias[n]   (bf16 in, bf16 out)
// M=4096 N=4096 K=1024. Block tile 256x128, 4 waves 2x2, wave-tile 128x64
// via 8x4 of 16x16x32 MFMA. DOUBLE-BUFFERED LDS, BK=32 (2 x 24 KB = 48 KB,
// occupancy unchanged vs R6), ONE barrier per stage. Order per stage:
// ds_read(cur) -> issue async prefetch(nxt) -> 32 MFMA -> barrier, so the
// barrier's vmcnt(0) drain waits on loads issued a full MFMA-block earlier.
// 4-seg XOR swizzle (phys = log ^ ((row>>1)&3)) on the GLOBAL source side,
// undone on ds_read -- R2-measured ZERO conflicts. z selects i2h/h2h.
// ---------------------------------------------------------------------------
__global__ __launch_bounds__(256, 2) void gemm_bias_bf16(
    const unsigned short* __restrict__ A0, const unsigned short* __restrict__ B0,
    const float* __restrict__ bias0, unsigned short* __restrict__ C0,
    const unsigned short* __restrict__ A1, const unsigned short* __restrict__ B1,
    const float* __restrict__ bias1, unsigned short* __restrict__ C1)
{
    const unsigned short* A  = blockIdx.z ? A1 : A0;
    const unsigned short* Bt = blockIdx.z ? B1 : B0;
    const float* bias        = blockIdx.z ? bias1 : bias0;
    unsigned short* C        = blockIdx.z ? C1 : C0;

    __shared__ __align__(16) unsigned short Als[2][256 * 32];   // 2 x 16 KB
    __shared__ __align__(16) unsigned short Bls[2][128 * 32];   // 2 x  8 KB

    const int tid  = threadIdx.x;
    const int wid  = tid >> 6;
    const int lane = tid & 63;
    const int bm = blockIdx.x;      // 0..15 (256-row tiles)
    const int bn = blockIdx.y;      // 0..31 (128-col tiles)

    const int wr = wid >> 1;        // wave row: rows wr*128
    const int wc = wid & 1;         // wave col: cols wc*64

    f32x4 acc[8][4] = {};

    // ---- staging: each async16 covers 64 rows x 32 cols; this thread's row
    // within a call = wid*16 + (lane>>2); global k-seg XOR-swizzled:
    // sseg = (lane&3) ^ ((row>>1)&3) = (lane&3) ^ ((lane>>3)&3)  [lane-pure]
    const int sseg = ((lane & 3) ^ ((lane >> 3) & 3)) * 8;
    const int srow = wid * 16 + (lane >> 2);
    const unsigned short* Ag = A  + (size_t)(bm * 256 + srow) * KDIM + sseg;
    const unsigned short* Bg = Bt + (size_t)(bn * 128 + srow) * KDIM + sseg;
    const int ldsW = (wid * 16) * 32;   // wave-uniform base (elems)

    // ---- fragment offsets (R2-proven conflict-free pattern):
    // frag row = base + mi*16 + (lane&15); logical k-seg q = lane>>4;
    // phys = q ^ ((row>>1)&3) = q ^ (((lane&15)>>1)&3)
    const int q  = lane >> 4;
    const int fr = lane & 15;
    const int ph = (q ^ ((fr >> 1) & 3)) * 8;
    int aOff[8], bOff[4];
    #pragma unroll
    for (int mi = 0; mi < 8; ++mi) aOff[mi] = (wr * 128 + mi * 16 + fr) * 32 + ph;
    #pragma unroll
    for (int ni = 0; ni < 4; ++ni) bOff[ni] = (wc * 64 + ni * 16 + fr) * 32 + ph;

    // prologue: stage 0 -> buf 0
    #pragma unroll
    for (int i = 0; i < 4; ++i)
        async16(Ag + (size_t)(i * 64) * KDIM, &Als[0][ldsW + i * 64 * 32]);
    #pragma unroll
    for (int i = 0; i < 2; ++i)
        async16(Bg + (size_t)(i * 64) * KDIM, &Bls[0][ldsW + i * 64 * 32]);
    __syncthreads();

    for (int k0 = 0; k0 < KDIM; k0 += 32) {
        const int cur = (k0 >> 5) & 1;

        // 1) read current-stage fragments
        bf16x8 af[8], bfv[4];
        #pragma unroll
        for (int mi = 0; mi < 8; ++mi) af[mi]  = *(const bf16x8*)&Als[cur][aOff[mi]];
        #pragma unroll
        for (int ni = 0; ni < 4; ++ni) bfv[ni] = *(const bf16x8*)&Bls[cur][bOff[ni]];

        // 2) issue prefetch of next stage into the other buffer
        if (k0 + 32 < KDIM) {
            const int nxt = cur ^ 1;
            #pragma unroll
            for (int i = 0; i < 4; ++i)
                async16(Ag + k0 + 32 + (size_t)(i * 64) * KDIM,
                        &Als[nxt][ldsW + i * 64 * 32]);
            #pragma unroll
            for (int i = 0; i < 2; ++i)
                async16(Bg + k0 + 32 + (size_t)(i * 64) * KDIM,
                        &Bls[nxt][ldsW + i * 64 * 32]);
        }

        // 3) MFMA block covers the prefetch flight
        #pragma unroll
        for (int mi = 0; mi < 8; ++mi)
            #pragma unroll
            for (int ni = 0; ni < 4; ++ni)
                acc[mi][ni] = __builtin_amdgcn_mfma_f32_16x16x32_bf16(
                    af[mi], bfv[ni], acc[mi][ni], 0, 0, 0);

        // 4) one barrier per stage (drain of iter-old loads)
        __syncthreads();
    }

    // ---- epilogue (R2-proven 16x16 layout): D[row=(lane>>4)*4+r][col=lane&15]
    const int rb = wr * 128 + (lane >> 4) * 4;
    const int cb = wc * 64 + (lane & 15);
    float bv[4];
    #pragma unroll
    for (int ni = 0; ni < 4; ++ni) bv[ni] = bias[bn * 128 + cb + ni * 16];
    #pragma unroll
    for (int mi = 0; mi < 8; ++mi) {
        #pragma unroll
        for (int r = 0; r < 4; ++r) {
            size_t grow = (size_t)(bm * 256 + rb + mi * 16 + r) * NDIM;
            #pragma unroll
            for (int ni = 0; ni < 4; ++ni)
                C[grow + bn * 128 + cb + ni * 16] = f2bf(acc[mi][ni][r] + bv[ni]);
        }
    }
}

// ---------------------------------------------------------------------------
// fused LN(hi)+LN(hh)+gates+LN(cell)+outputs. TWO rows per block:
// sub = tid>>7 selects row, t = tid&127 covers 8 cols per gate (16B loads).
// ---------------------------------------------------------------------------
__global__ __launch_bounds__(256) void ln_gates(
    const unsigned short* __restrict__ hi_pre, const unsigned short* __restrict__ hh_pre,
    const float* __restrict__ c_prev,
    const float* __restrict__ g1, const float* __restrict__ be1,
    const float* __restrict__ g2, const float* __restrict__ be2,
    const float* __restrict__ gc, const float* __restrict__ bec,
    float* __restrict__ h_out, float* __restrict__ c_out)
{
    __shared__ float sm[16];
    const int tid = threadIdx.x;
    const int sub = tid >> 7, t = tid & 127;
    const int wv = tid >> 6, lane = tid & 63;
    const int row = blockIdx.x * 2 + sub;
    const unsigned short* hir = hi_pre + (size_t)row * NDIM;
    const unsigned short* hhr = hh_pre + (size_t)row * NDIM;

    u16x8 vi[4], vh[4];
    float s1 = 0.f, ss1 = 0.f, s2 = 0.f, ss2 = 0.f;
    #pragma unroll
    for (int q = 0; q < 4; ++q) {
        int col = q * 1024 + t * 8;
        vi[q] = *(const u16x8*)(hir + col);
        vh[q] = *(const u16x8*)(hhr + col);
        #pragma unroll
        for (int j = 0; j < 8; ++j) {
            float a = bf2f(vi[q][j]), b = bf2f(vh[q][j]);
            s1 += a; ss1 += a * a; s2 += b; ss2 += b * b;
        }
    }
    #pragma unroll
    for (int off = 32; off > 0; off >>= 1) {
        s1 += __shfl_down(s1, off, 64);
        ss1 += __shfl_down(ss1, off, 64);
        s2 += __shfl_down(s2, off, 64);
        ss2 += __shfl_down(ss2, off, 64);
    }
    if (lane == 0) {
        sm[wv * 4 + 0] = s1; sm[wv * 4 + 1] = ss1;
        sm[wv * 4 + 2] = s2; sm[wv * 4 + 3] = ss2;
    }
    __syncthreads();
    const int base = sub * 8;
    float R1 = sm[base + 0] + sm[base + 4];
    float Q1 = sm[base + 1] + sm[base + 5];
    float R2 = sm[base + 2] + sm[base + 6];
    float Q2 = sm[base + 3] + sm[base + 7];

    const float n1 = (float)NDIM;
    float m1 = R1 / n1;
    float v1 = (Q1 - n1 * m1 * m1) / (n1 - 1.f);
    float r1 = 1.0f / (sqrtf(fmaxf(v1, 0.f)) + EPSV);
    float m2 = R2 / n1;
    float v2 = (Q2 - n1 * m2 * m2) / (n1 - 1.f);
    float r2 = 1.0f / (sqrtf(fmaxf(v2, 0.f)) + EPSV);

    float gate[4][8];
    #pragma unroll
    for (int q = 0; q < 4; ++q) {
        int col = q * 1024 + t * 8;
        float4 G1a = *(const float4*)(g1 + col),  G1b = *(const float4*)(g1 + col + 4);
        float4 B1a = *(const float4*)(be1 + col), B1b = *(const float4*)(be1 + col + 4);
        float4 G2a = *(const float4*)(g2 + col),  G2b = *(const float4*)(g2 + col + 4);
        float4 B2a = *(const float4*)(be2 + col), B2b = *(const float4*)(be2 + col + 4);
        float G1[8] = {G1a.x, G1a.y, G1a.z, G1a.w, G1b.x, G1b.y, G1b.z, G1b.w};
        float B1[8] = {B1a.x, B1a.y, B1a.z, B1a.w, B1b.x, B1b.y, B1b.z, B1b.w};
        float G2[8] = {G2a.x, G2a.y, G2a.z, G2a.w, G2b.x, G2b.y, G2b.z, G2b.w};
        float B2[8] = {B2a.x, B2a.y, B2a.z, B2a.w, B2b.x, B2b.y, B2b.z, B2b.w};
        #pragma unroll
        for (int j = 0; j < 8; ++j)
            gate[q][j] = G1[j] * (bf2f(vi[q][j]) - m1) * r1 + B1[j]
                       + G2[j] * (bf2f(vh[q][j]) - m2) * r2 + B2[j];
    }

    float4 cpa = *(const float4*)(c_prev + (size_t)row * 1024 + t * 8);
    float4 cpb = *(const float4*)(c_prev + (size_t)row * 1024 + t * 8 + 4);
    float cpv[8] = {cpa.x, cpa.y, cpa.z, cpa.w, cpb.x, cpb.y, cpb.z, cpb.w};
    float a[8];
    float s3 = 0.f, ss3 = 0.f;
    #pragma unroll
    for (int j = 0; j < 8; ++j) {
        a[j] = cpv[j] * sigm(gate[1][j] + 1.0f) + ftanh(gate[2][j]) * sigm(gate[0][j]);
        s3 += a[j]; ss3 += a[j] * a[j];
    }
    #pragma unroll
    for (int off = 32; off > 0; off >>= 1) {
        s3 += __shfl_down(s3, off, 64);
        ss3 += __shfl_down(ss3, off, 64);
    }
    __syncthreads();   // sm reuse
    if (lane == 0) { sm[wv * 2 + 0] = s3; sm[wv * 2 + 1] = ss3; }
    __syncthreads();
    const int b2 = sub * 4;
    float R3 = sm[b2 + 0] + sm[b2 + 2];
    float Q3 = sm[b2 + 1] + sm[b2 + 3];
    const float n3 = 1024.f;
    float m3 = R3 / n3;
    float v3 = (Q3 - n3 * m3 * m3) / (n3 - 1.f);
    float r3 = 1.0f / (sqrtf(fmaxf(v3, 0.f)) + EPSV);

    int colh = t * 8;
    float4 GCa = *(const float4*)(gc + colh),  GCb = *(const float4*)(gc + colh + 4);
    float4 BCa = *(const float4*)(bec + colh), BCb = *(const float4*)(bec + colh + 4);
    float GC[8] = {GCa.x, GCa.y, GCa.z, GCa.w, GCb.x, GCb.y, GCb.z, GCb.w};
    float BC[8] = {BCa.x, BCa.y, BCa.z, BCa.w, BCb.x, BCb.y, BCb.z, BCb.w};
    float cj[8], hj[8];
    #pragma unroll
    for (int j = 0; j < 8; ++j) {
        cj[j] = GC[j] * (a[j] - m3) * r3 + BC[j];
        hj[j] = sigm(gate[3][j]) * ftanh(cj[j]);
    }
    float4 hva = {hj[0], hj[1], hj[2], hj[3]}, hvb = {hj[4], hj[5], hj[6], hj[7]};
    float4 cva = {cj[0], cj[1], cj[2], cj[3]}, cvb = {cj[4], cj[5], cj[6], cj[7]};
    *(float4*)(h_out + (size_t)row * 1024 + colh) = hva;
    *(float4*)(h_out + (size_t)row * 1024 + colh + 4) = hvb;
    *(float4*)(c_out + (size_t)row * 1024 + colh) = cva;
    *(float4*)(c_out + (size_t)row * 1024 + colh + 4) = cvb;
}

// ---------------------------------------------------------------------------
extern "C" void kernel_launch(void* const* d_in, const int* in_sizes, int n_in,
                              void* d_out, int out_size, void* d_ws, size_t ws_size,
                              hipStream_t stream) {
    const float* input  = (const float*)d_in[0];
    const float* h_prev = (const float*)d_in[1];
    const float* c_prev = (const float*)d_in[2];
    const float* w_i2h  = (const float*)d_in[3];
    const float* b_i2h  = (const float*)d_in[4];
    const float* w_h2h  = (const float*)d_in[5];
    const float* b_h2h  = (const float*)d_in[6];
    const float* g_i2h  = (const float*)d_in[7];
    const float* be_i2h = (const float*)d_in[8];
    const float* g_h2h  = (const float*)d_in[9];
    const float* be_h2h = (const float*)d_in[10];
    const float* g_c    = (const float*)d_in[11];
    const float* be_c   = (const float*)d_in[12];

    const size_t MK = (size_t)BDIM * KDIM;       // 4M
    const size_t MN = (size_t)BDIM * NDIM;       // 16M

    unsigned short* inA    = (unsigned short*)d_ws;
    unsigned short* inH    = inA + MK;
    unsigned short* w1T    = inH + MK;           // [N][K]
    unsigned short* w2T    = w1T + MK;
    unsigned short* hi_pre = w2T + MK;           // [B][4H] bf16
    unsigned short* hh_pre = hi_pre + MN;        // total 96 MB

    float* h_out = (float*)d_out;
    float* c_out = h_out + (size_t)BDIM * 1024;

    prep<<<dim3(2048, 1, 4), 256, 0, stream>>>(
        input, inA, h_prev, inH, w_i2h, w1T, w_h2h, w2T);

    gemm_bias_bf16<<<dim3(16, 32, 2), 256, 0, stream>>>(
        inA, w1T, b_i2h, hi_pre, inH, w2T, b_h2h, hh_pre);

    ln_gates<<<2048, 256, 0, stream>>>(
        hi_pre, hh_pre, c_prev, g_i2h, be_i2h, g_h2h, be_h2h, g_c, be_c, h_out, c_out);
}

// Round 8
// 237.905 us; speedup vs baseline: 1.0484x; 1.0484x over previous
//
#include <hip/hip_runtime.h>
#include <hip/hip_bf16.h>
#include <stdint.h>

// ---------------------------------------------------------------------------
// LayerNormLSTMCell: B=4096, I=H=1024, 4H=4096
//  hi = LN(input @ w_i2h + b_i2h; g_i2h, be_i2h)        [B,4H]
//  hh = LN(h_prev @ w_h2h + b_h2h; g_h2h, be_h2h)       [B,4H]
//  i,f,u,o = split(hi+hh, 4)
//  c = LN(c_prev*sigm(f+1) + tanh(u)*sigm(i); g_c,be_c) [B,H]
//  h = sigm(o)*tanh(c)
// LN: mean, UNBIASED std (ddof=1), divide by (std + 1e-6)
//
// R8 = R6 revert (best measured config: gemm 73.4 us, 0 LDS conflicts,
// MfmaUtil 40.5%). R7's explicit double-buffer regressed (-9 us) confirming
// the documented m99/m100/m131-141 plateau of this K-loop structure.
// ---------------------------------------------------------------------------

#define BDIM 4096
#define KDIM 1024
#define NDIM 4096
#define EPSV 1e-6f

typedef float f32x4 __attribute__((ext_vector_type(4)));
typedef __bf16 bf16x8 __attribute__((ext_vector_type(8)));
typedef unsigned short u16x8 __attribute__((ext_vector_type(8)));

__device__ inline unsigned short f2bf(float f) {
    unsigned u = __builtin_bit_cast(unsigned, f);
    u += 0x7FFFu + ((u >> 16) & 1u);   // round-to-nearest-even
    return (unsigned short)(u >> 16);
}
__device__ inline float bf2f(unsigned short u) {
    return __builtin_bit_cast(float, (unsigned)u << 16);
}
__device__ inline float sigm(float x) {
    return 1.0f / (1.0f + __expf(-x));
}
// fast tanh: 1 - 2/(e^{2x}+1); saturates correctly at +-inf
__device__ inline float ftanh(float x) {
    return 1.0f - 2.0f / (__expf(2.0f * x) + 1.0f);
}

// async global->LDS, 16B per lane. lds ptr must be wave-uniform.
__device__ inline void async16(const unsigned short* g, unsigned short* lds) {
    __builtin_amdgcn_global_load_lds(
        (const __attribute__((address_space(1))) void*)g,
        (__attribute__((address_space(3))) void*)lds,
        16, 0, 0);
}

// ---------------------------------------------------------------------------
// prep: z=0/1 cast input/h_prev f32->bf16 (8 elem/thread, 16B stores)
//       z=2/3 transpose+cast w f32 [1024][4096] -> bf16 [4096][1024]
// ---------------------------------------------------------------------------
__global__ __launch_bounds__(256) void prep(
    const float* __restrict__ in0, unsigned short* __restrict__ o0,
    const float* __restrict__ in1, unsigned short* __restrict__ o1,
    const float* __restrict__ w0, unsigned short* __restrict__ w0T,
    const float* __restrict__ w1, unsigned short* __restrict__ w1T)
{
    __shared__ float tile[64][65];
    const int z = blockIdx.z, tid = threadIdx.x;
    if (z < 2) {
        const float* src = z ? in1 : in0;
        unsigned short* dst = z ? o1 : o0;
        int i = (blockIdx.x * 256 + tid) * 8;
        float4 a = *(const float4*)(src + i);
        float4 b = *(const float4*)(src + i + 4);
        u16x8 v;
        v[0] = f2bf(a.x); v[1] = f2bf(a.y); v[2] = f2bf(a.z); v[3] = f2bf(a.w);
        v[4] = f2bf(b.x); v[5] = f2bf(b.y); v[6] = f2bf(b.z); v[7] = f2bf(b.w);
        *(u16x8*)(dst + i) = v;
        return;
    }
    const int bx = blockIdx.x;
    if (bx >= (NDIM / 64) * (KDIM / 64)) return;
    const float* src = (z == 3) ? w1 : w0;
    unsigned short* dst = (z == 3) ? w1T : w0T;
    const int c0 = (bx & (NDIM / 64 - 1)) * 64;   // col in [0,4096)
    const int r0 = (bx >> 6) * 64;                // row in [0,1024)
    const int tx = tid & 63, ty = tid >> 6;       // 64 x 4
    #pragma unroll
    for (int i = 0; i < 64; i += 4)
        tile[ty + i][tx] = src[(size_t)(r0 + ty + i) * NDIM + c0 + tx];
    __syncthreads();
    #pragma unroll
    for (int p = 0; p < 2; ++p) {
        int c = p * 32 + (tid >> 3);
        int rs = (tid & 7) * 8;
        u16x8 v;
        #pragma unroll
        for (int j = 0; j < 8; ++j) v[j] = f2bf(tile[rs + j][c]);
        *(u16x8*)(dst + (size_t)(c0 + c) * KDIM + r0 + rs) = v;
    }
}

// ---------------------------------------------------------------------------
// GEMM: C[m][n] = sum_k A[m][k] * Bt[n][k] + bias[n]   (bf16 in, bf16 out)
// M=4096 N=4096 K=1024. Block tile 256x128, BK=64, 4 waves in 2x2 grid,
// wave-tile 128x64 via 8x4 of 16x16x32 MFMA (acc 128 regs/lane).
// The 16x16 fragment read pattern (rows lane&15, phys seg = (s*4+q)^r7)
// measured ZERO bank conflicts (R4/R6); the 32x32 pattern measured 6.29M (R5).
// LDS: A 32KB + B 16KB, single-buffered (explicit dbuf regressed, R7).
// blockIdx.z selects problem (i2h vs h2h).
// ---------------------------------------------------------------------------
__global__ __launch_bounds__(256, 2) void gemm_bias_bf16(
    const unsigned short* __restrict__ A0, const unsigned short* __restrict__ B0,
    const float* __restrict__ bias0, unsigned short* __restrict__ C0,
    const unsigned short* __restrict__ A1, const unsigned short* __restrict__ B1,
    const float* __restrict__ bias1, unsigned short* __restrict__ C1)
{
    const unsigned short* A  = blockIdx.z ? A1 : A0;
    const unsigned short* Bt = blockIdx.z ? B1 : B0;
    const float* bias        = blockIdx.z ? bias1 : bias0;
    unsigned short* C        = blockIdx.z ? C1 : C0;

    __shared__ __align__(16) unsigned short Als[256 * 64];   // 32 KB
    __shared__ __align__(16) unsigned short Bls[128 * 64];   // 16 KB

    const int tid  = threadIdx.x;
    const int wid  = tid >> 6;
    const int lane = tid & 63;
    const int bm = blockIdx.x;      // 0..15 (256-row tiles)
    const int bn = blockIdx.y;      // 0..31 (128-col tiles)

    const int wr = wid >> 1;        // wave row: rows wr*128
    const int wc = wid & 1;         // wave col: cols wc*64

    f32x4 acc[8][4] = {};

    // ---- staging: each async16 covers 32 rows (8/wave); row = base+(lane>>3),
    // global k-seg XOR-swizzled: sseg = (lane&7)^(row&7), row&7 = lane>>3 ----
    const int sseg = (lane & 7) ^ (lane >> 3);
    const unsigned short* Abase =
        A + (size_t)(bm * 256 + wid * 8 + (lane >> 3)) * KDIM + sseg * 8;
    const unsigned short* Bbase =
        Bt + (size_t)(bn * 128 + wid * 8 + (lane >> 3)) * KDIM + sseg * 8;
    unsigned short* AldsU = Als + (wid * 8) * 64;   // wave-uniform
    unsigned short* BldsU = Bls + (wid * 8) * 64;

    // ---- fragment addressing (16x16x32, R4/R6-proven conflict-free):
    // frag row = base + mi*16 + (lane&15); row&7 = lane&7 = r7
    // logical k-seg = s*4 + q (q = lane>>4); phys = logical ^ r7 ----
    const int q    = lane >> 4;
    const int r7   = lane & 7;
    const int frow = lane & 15;
    const unsigned short* aRow[8];
    const unsigned short* bRow[4];
    #pragma unroll
    for (int mi = 0; mi < 8; ++mi)
        aRow[mi] = &Als[(wr * 128 + mi * 16 + frow) * 64];
    #pragma unroll
    for (int ni = 0; ni < 4; ++ni)
        bRow[ni] = &Bls[(wc * 64 + ni * 16 + frow) * 64];
    const int ph0 = ((q ^ r7)) * 8;        // k-seg 0 (s=0)
    const int ph1 = ((q ^ r7) ^ 4) * 8;    // k-seg 1 (s=1; s*4 flips bit 2)

    for (int k0 = 0; k0 < KDIM; k0 += 64) {
        #pragma unroll
        for (int i = 0; i < 8; ++i)
            async16(Abase + k0 + (size_t)(i * 32) * KDIM, AldsU + i * 32 * 64);
        #pragma unroll
        for (int j = 0; j < 4; ++j)
            async16(Bbase + k0 + (size_t)(j * 32) * KDIM, BldsU + j * 32 * 64);
        __syncthreads();

        #pragma unroll
        for (int s = 0; s < 2; ++s) {
            const int ph = s ? ph1 : ph0;
            bf16x8 af[8], bfv[4];
            #pragma unroll
            for (int mi = 0; mi < 8; ++mi)
                af[mi] = *(const bf16x8*)(aRow[mi] + ph);
            #pragma unroll
            for (int ni = 0; ni < 4; ++ni)
                bfv[ni] = *(const bf16x8*)(bRow[ni] + ph);
            #pragma unroll
            for (int mi = 0; mi < 8; ++mi)
                #pragma unroll
                for (int ni = 0; ni < 4; ++ni)
                    acc[mi][ni] = __builtin_amdgcn_mfma_f32_16x16x32_bf16(
                        af[mi], bfv[ni], acc[mi][ni], 0, 0, 0);
        }
        __syncthreads();
    }

    // ---- epilogue (R2-proven 16x16 layout): D[row=(lane>>4)*4+r][col=lane&15]
    const int rb = wr * 128 + (lane >> 4) * 4;
    const int cb = wc * 64 + (lane & 15);
    float bv[4];
    #pragma unroll
    for (int ni = 0; ni < 4; ++ni) bv[ni] = bias[bn * 128 + cb + ni * 16];
    #pragma unroll
    for (int mi = 0; mi < 8; ++mi) {
        #pragma unroll
        for (int r = 0; r < 4; ++r) {
            size_t grow = (size_t)(bm * 256 + rb + mi * 16 + r) * NDIM;
            #pragma unroll
            for (int ni = 0; ni < 4; ++ni)
                C[grow + bn * 128 + cb + ni * 16] = f2bf(acc[mi][ni][r] + bv[ni]);
        }
    }
}

// ---------------------------------------------------------------------------
// fused LN(hi)+LN(hh)+gates+LN(cell)+outputs. TWO rows per block:
// sub = tid>>7 selects row, t = tid&127 covers 8 cols per gate (16B loads).
// ---------------------------------------------------------------------------
__global__ __launch_bounds__(256) void ln_gates(
    const unsigned short* __restrict__ hi_pre, const unsigned short* __restrict__ hh_pre,
    const float* __restrict__ c_prev,
    const float* __restrict__ g1, const float* __restrict__ be1,
    const float* __restrict__ g2, const float* __restrict__ be2,
    const float* __restrict__ gc, const float* __restrict__ bec,
    float* __restrict__ h_out, float* __restrict__ c_out)
{
    __shared__ float sm[16];
    const int tid = threadIdx.x;
    const int sub = tid >> 7, t = tid & 127;
    const int wv = tid >> 6, lane = tid & 63;
    const int row = blockIdx.x * 2 + sub;
    const unsigned short* hir = hi_pre + (size_t)row * NDIM;
    const unsigned short* hhr = hh_pre + (size_t)row * NDIM;

    u16x8 vi[4], vh[4];
    float s1 = 0.f, ss1 = 0.f, s2 = 0.f, ss2 = 0.f;
    #pragma unroll
    for (int q = 0; q < 4; ++q) {
        int col = q * 1024 + t * 8;
        vi[q] = *(const u16x8*)(hir + col);
        vh[q] = *(const u16x8*)(hhr + col);
        #pragma unroll
        for (int j = 0; j < 8; ++j) {
            float a = bf2f(vi[q][j]), b = bf2f(vh[q][j]);
            s1 += a; ss1 += a * a; s2 += b; ss2 += b * b;
        }
    }
    #pragma unroll
    for (int off = 32; off > 0; off >>= 1) {
        s1 += __shfl_down(s1, off, 64);
        ss1 += __shfl_down(ss1, off, 64);
        s2 += __shfl_down(s2, off, 64);
        ss2 += __shfl_down(ss2, off, 64);
    }
    if (lane == 0) {
        sm[wv * 4 + 0] = s1; sm[wv * 4 + 1] = ss1;
        sm[wv * 4 + 2] = s2; sm[wv * 4 + 3] = ss2;
    }
    __syncthreads();
    const int base = sub * 8;
    float R1 = sm[base + 0] + sm[base + 4];
    float Q1 = sm[base + 1] + sm[base + 5];
    float R2 = sm[base + 2] + sm[base + 6];
    float Q2 = sm[base + 3] + sm[base + 7];

    const float n1 = (float)NDIM;
    float m1 = R1 / n1;
    float v1 = (Q1 - n1 * m1 * m1) / (n1 - 1.f);
    float r1 = 1.0f / (sqrtf(fmaxf(v1, 0.f)) + EPSV);
    float m2 = R2 / n1;
    float v2 = (Q2 - n1 * m2 * m2) / (n1 - 1.f);
    float r2 = 1.0f / (sqrtf(fmaxf(v2, 0.f)) + EPSV);

    float gate[4][8];
    #pragma unroll
    for (int q = 0; q < 4; ++q) {
        int col = q * 1024 + t * 8;
        float4 G1a = *(const float4*)(g1 + col),  G1b = *(const float4*)(g1 + col + 4);
        float4 B1a = *(const float4*)(be1 + col), B1b = *(const float4*)(be1 + col + 4);
        float4 G2a = *(const float4*)(g2 + col),  G2b = *(const float4*)(g2 + col + 4);
        float4 B2a = *(const float4*)(be2 + col), B2b = *(const float4*)(be2 + col + 4);
        float G1[8] = {G1a.x, G1a.y, G1a.z, G1a.w, G1b.x, G1b.y, G1b.z, G1b.w};
        float B1[8] = {B1a.x, B1a.y, B1a.z, B1a.w, B1b.x, B1b.y, B1b.z, B1b.w};
        float G2[8] = {G2a.x, G2a.y, G2a.z, G2a.w, G2b.x, G2b.y, G2b.z, G2b.w};
        float B2[8] = {B2a.x, B2a.y, B2a.z, B2a.w, B2b.x, B2b.y, B2b.z, B2b.w};
        #pragma unroll
        for (int j = 0; j < 8; ++j)
            gate[q][j] = G1[j] * (bf2f(vi[q][j]) - m1) * r1 + B1[j]
                       + G2[j] * (bf2f(vh[q][j]) - m2) * r2 + B2[j];
    }

    float4 cpa = *(const float4*)(c_prev + (size_t)row * 1024 + t * 8);
    float4 cpb = *(const float4*)(c_prev + (size_t)row * 1024 + t * 8 + 4);
    float cpv[8] = {cpa.x, cpa.y, cpa.z, cpa.w, cpb.x, cpb.y, cpb.z, cpb.w};
    float a[8];
    float s3 = 0.f, ss3 = 0.f;
    #pragma unroll
    for (int j = 0; j < 8; ++j) {
        a[j] = cpv[j] * sigm(gate[1][j] + 1.0f) + ftanh(gate[2][j]) * sigm(gate[0][j]);
        s3 += a[j]; ss3 += a[j] * a[j];
    }
    #pragma unroll
    for (int off = 32; off > 0; off >>= 1) {
        s3 += __shfl_down(s3, off, 64);
        ss3 += __shfl_down(ss3, off, 64);
    }
    __syncthreads();   // sm reuse
    if (lane == 0) { sm[wv * 2 + 0] = s3; sm[wv * 2 + 1] = ss3; }
    __syncthreads();
    const int b2 = sub * 4;
    float R3 = sm[b2 + 0] + sm[b2 + 2];
    float Q3 = sm[b2 + 1] + sm[b2 + 3];
    const float n3 = 1024.f;
    float m3 = R3 / n3;
    float v3 = (Q3 - n3 * m3 * m3) / (n3 - 1.f);
    float r3 = 1.0f / (sqrtf(fmaxf(v3, 0.f)) + EPSV);

    int colh = t * 8;
    float4 GCa = *(const float4*)(gc + colh),  GCb = *(const float4*)(gc + colh + 4);
    float4 BCa = *(const float4*)(bec + colh), BCb = *(const float4*)(bec + colh + 4);
    float GC[8] = {GCa.x, GCa.y, GCa.z, GCa.w, GCb.x, GCb.y, GCb.z, GCb.w};
    float BC[8] = {BCa.x, BCa.y, BCa.z, BCa.w, BCb.x, BCb.y, BCb.z, BCb.w};
    float cj[8], hj[8];
    #pragma unroll
    for (int j = 0; j < 8; ++j) {
        cj[j] = GC[j] * (a[j] - m3) * r3 + BC[j];
        hj[j] = sigm(gate[3][j]) * ftanh(cj[j]);
    }
    float4 hva = {hj[0], hj[1], hj[2], hj[3]}, hvb = {hj[4], hj[5], hj[6], hj[7]};
    float4 cva = {cj[0], cj[1], cj[2], cj[3]}, cvb = {cj[4], cj[5], cj[6], cj[7]};
    *(float4*)(h_out + (size_t)row * 1024 + colh) = hva;
    *(float4*)(h_out + (size_t)row * 1024 + colh + 4) = hvb;
    *(float4*)(c_out + (size_t)row * 1024 + colh) = cva;
    *(float4*)(c_out + (size_t)row * 1024 + colh + 4) = cvb;
}

// ---------------------------------------------------------------------------
extern "C" void kernel_launch(void* const* d_in, const int* in_sizes, int n_in,
                              void* d_out, int out_size, void* d_ws, size_t ws_size,
                              hipStream_t stream) {
    const float* input  = (const float*)d_in[0];
    const float* h_prev = (const float*)d_in[1];
    const float* c_prev = (const float*)d_in[2];
    const float* w_i2h  = (const float*)d_in[3];
    const float* b_i2h  = (const float*)d_in[4];
    const float* w_h2h  = (const float*)d_in[5];
    const float* b_h2h  = (const float*)d_in[6];
    const float* g_i2h  = (const float*)d_in[7];
    const float* be_i2h = (const float*)d_in[8];
    const float* g_h2h  = (const float*)d_in[9];
    const float* be_h2h = (const float*)d_in[10];
    const float* g_c    = (const float*)d_in[11];
    const float* be_c   = (const float*)d_in[12];

    const size_t MK = (size_t)BDIM * KDIM;       // 4M
    const size_t MN = (size_t)BDIM * NDIM;       // 16M

    unsigned short* inA    = (unsigned short*)d_ws;
    unsigned short* inH    = inA + MK;
    unsigned short* w1T    = inH + MK;           // [N][K]
    unsigned short* w2T    = w1T + MK;
    unsigned short* hi_pre = w2T + MK;           // [B][4H] bf16
    unsigned short* hh_pre = hi_pre + MN;        // total 96 MB

    float* h_out = (float*)d_out;
    float* c_out = h_out + (size_t)BDIM * 1024;

    prep<<<dim3(2048, 1, 4), 256, 0, stream>>>(
        input, inA, h_prev, inH, w_i2h, w1T, w_h2h, w2T);

    gemm_bias_bf16<<<dim3(16, 32, 2), 256, 0, stream>>>(
        inA, w1T, b_i2h, hi_pre, inH, w2T, b_h2h, hh_pre);

    ln_gates<<<2048, 256, 0, stream>>>(
        hi_pre, hh_pre, c_prev, g_i2h, be_i2h, g_h2h, be_h2h, g_c, be_c, h_out, c_out);
}